// Round 6
// baseline (81.328 us; speedup 1.0000x reference)
//
#include <hip/hip_runtime.h>
#include <math.h>

// SoAGREE fused forward. One block (256 thr = 4 waves) per batch element.
// B=1024, M=16, F=32, D=64, fp32.
// Wave w owns members 4w..4w+3 as two pairs. BOTH pair tiles are resident
// (double-buffered, 128 KB dynamic LDS total) and both STAGEs issue up
// front; consumption uses counted vmcnt(16)/vmcnt(0) so pair1's 16 KB DMA
// streams under pair0's score MLP. Score MLP: row-per-lane from LDS tile,
// fatt_w1 streamed as wave-uniform SGPR operands. Column reduction:
// register butterfly over the 32 f-lanes.

#define LDS_FLOATS 35888   // 143552 bytes

__global__ __launch_bounds__(256, 1) void soagree_kernel(
    const int* __restrict__ group_inputs,   // [B]
    const int* __restrict__ item_inputs,    // [B]
    const int* __restrict__ member_ids,     // [B,16]
    const int* __restrict__ follow_ids,     // [B,16,32]
    const float* __restrict__ user_table,   // [NU,64]
    const float* __restrict__ item_table,   // [NI,64]
    const float* __restrict__ group_table,  // [NG,64]
    const float* __restrict__ follow_table, // [NU,64]
    const float* __restrict__ fatt_w1, const float* __restrict__ fatt_b1,
    const float* __restrict__ fatt_w2, const float* __restrict__ fatt_b2,
    const float* __restrict__ att_w1,  const float* __restrict__ att_b1,
    const float* __restrict__ att_w2,  const float* __restrict__ att_b2,
    const float* __restrict__ pred_w1, const float* __restrict__ pred_b1,
    const float* __restrict__ pred_w2, const float* __restrict__ pred_b2,
    float* __restrict__ out)               // [B]
{
    const int b    = blockIdx.x;
    const int tid  = threadIdx.x;
    const int w    = tid >> 6;    // wave id 0..3
    const int lane = tid & 63;
    const int f    = lane & 31;   // follow row within member
    const int mh   = lane >> 5;   // which member of the pair

    extern __shared__ float smem[];
    float* const s_tile  = smem;                  // [4 waves][2 pairs][4096]
    int*   const s_ids   = (int*)(smem + 32768);  // [4][128]
    float* const s_uemb  = smem + 33280;          // [16][66]
    float* const s_mem   = smem + 34336;          // [16][66]
    float* const s_upart = smem + 35392;          // [16][16]
    float* const s_ipart = smem + 35648;          // [16]
    float* const s_iemb  = smem + 35664;          // [64]
    float* const s_gemb  = smem + 35728;          // [64]
    float* const s_gfin  = smem + 35792;          // [64]
    float* const s_score = smem + 35856;          // [16]
    float* const s_mw    = smem + 35872;          // [16]

    float* const mytile = s_tile + w * 8192;

    // ---- phase 0 (wave-local): ids, own uemb, iemb/gemb ----
    if (tid < 64) {
        s_iemb[tid] = item_table[(size_t)item_inputs[b] * 64 + tid];
    } else if (tid < 128) {
        s_gemb[tid - 64] = group_table[(size_t)group_inputs[b] * 64 + (tid - 64)];
    }
    s_ids[w * 128 + lane]      = follow_ids[b * 512 + 128 * w + lane];
    s_ids[w * 128 + lane + 64] = follow_ids[b * 512 + 128 * w + lane + 64];
    #pragma unroll
    for (int it = 0; it < 4; ++it) {
        const int m   = w * 4 + it;
        const int uid = member_ids[b * 16 + m];          // wave-uniform -> s_load
        s_uemb[m * 66 + lane] = user_table[(size_t)uid * 64 + lane];
    }

    // ---- phase 0.5 (wave-local, BEFORE staging so its vector loads retire
    //      and the counted vmcnt below sees only STAGE loads) ----
    {
        int m = tid >> 4, j = tid & 15;      // wave w handles m = 4w..4w+3
        float acc = fatt_b1[j];
        #pragma unroll
        for (int d = 0; d < 64; ++d)
            acc += s_uemb[m * 66 + d] * fatt_w1[(64 + d) * 16 + j];
        s_upart[m * 16 + j] = acc;
    }
    if (tid < 16) {
        float a2 = att_b1[tid];
        #pragma unroll
        for (int d = 0; d < 64; ++d)
            a2 += s_iemb[d] * att_w1[(64 + d) * 16 + tid];
        s_ipart[tid] = a2;
    }

    // STAGE: 16 global_load_lds (16B each) for pair pr into buffer pr.
    // Physical 16B chunk s of row r holds logical chunk (s ^ (r&7)).
    #define STAGE(pr)                                                          \
    {                                                                          \
        _Pragma("unroll")                                                      \
        for (int g = 0; g < 16; ++g) {                                         \
            const int r   = 4 * g + (lane >> 4);                               \
            const int fid = s_ids[w * 128 + (pr) * 64 + r];                    \
            const int swz = (lane & 15) ^ (r & 7);                             \
            const float* gp = follow_table + (size_t)fid * 64 + (swz << 2);    \
            __builtin_amdgcn_global_load_lds(                                  \
                (const __attribute__((address_space(1))) void*)gp,             \
                (__attribute__((address_space(3))) void*)                      \
                    (mytile + (pr) * 4096 + g * 256),                          \
                16, 0, 0);                                                     \
        }                                                                      \
    }

    STAGE(0)
    STAGE(1)
    #undef STAGE

    const float fb2  = fatt_b2[0];
    const int   rrow = (mh << 5) | f;    // this lane's row in its pair tile
    const int   sw   = f & 7;            // read-back XOR

    // ---- phase 1: two pairs, counted-vmcnt pipeline, barrier-free ----
    #pragma unroll
    for (int pr = 0; pr < 2; ++pr) {
        const int pb = w * 4 + pr * 2;   // pair's first member
        const int m  = pb + mh;          // this lane's member

        if (pr == 0) { asm volatile("s_waitcnt vmcnt(16)" ::: "memory"); }
        else         { asm volatile("s_waitcnt vmcnt(0)"  ::: "memory"); }
        __builtin_amdgcn_sched_barrier(0);

        // read my row into regs (16 x ds_read_b128, swizzle-matched)
        const float* tp = mytile + pr * 4096 + rrow * 64;
        float4 r4[16];
        #pragma unroll
        for (int q = 0; q < 16; ++q)
            r4[q] = *(const float4*)&tp[(q ^ sw) << 2];
        float* rf = (float*)r4;

        // hacc init from s_upart
        float hacc[16];
        #pragma unroll
        for (int jj = 0; jj < 4; ++jj) {
            float4 up = *(const float4*)&s_upart[m * 16 + jj * 4];
            hacc[jj * 4 + 0] = up.x; hacc[jj * 4 + 1] = up.y;
            hacc[jj * 4 + 2] = up.z; hacc[jj * 4 + 3] = up.w;
        }

        // score MLP: d wave-uniform -> fatt_w1[d*16+j] streams as SGPR
        #pragma unroll
        for (int d = 0; d < 64; ++d) {
            const float v = rf[d];
            #pragma unroll
            for (int j = 0; j < 16; ++j)
                hacc[j] += v * fatt_w1[d * 16 + j];
        }
        float sc = fb2;
        #pragma unroll
        for (int j = 0; j < 16; ++j)
            sc += fmaxf(hacc[j], 0.f) * fatt_w2[j];

        // softmax over the 32 f-lanes of this half
        float mx = sc;
        #pragma unroll
        for (int mk = 16; mk >= 1; mk >>= 1) mx = fmaxf(mx, __shfl_xor(mx, mk));
        const float e = __expf(sc - mx);
        float se = e;
        #pragma unroll
        for (int mk = 16; mk >= 1; mk >>= 1) se += __shfl_xor(se, mk);
        const float fwv = e / se;

        // pre-scale row, then register butterfly: after 5 steps lane f holds
        // column sums for d = 2f, 2f+1 of its member.
        #pragma unroll
        for (int d = 0; d < 64; ++d) rf[d] *= fwv;

        #define BSTEP(M, S)                                                  \
        {                                                                    \
            const bool hi = (lane & (M)) != 0;                               \
            _Pragma("unroll")                                                \
            for (int k = 0; k < (S) / 2; ++k) {                              \
                float send = hi ? rf[k] : rf[k + (S) / 2];                   \
                float recv = __shfl_xor(send, (M));                          \
                float keep = hi ? rf[k + (S) / 2] : rf[k];                   \
                rf[k] = keep + recv;                                         \
            }                                                                \
        }
        BSTEP(16, 64)
        BSTEP(8, 32)
        BSTEP(4, 16)
        BSTEP(2, 8)
        BSTEP(1, 4)
        #undef BSTEP

        float2 ue = *(const float2*)&s_uemb[m * 66 + 2 * f];
        float2 res; res.x = rf[0] + ue.x; res.y = rf[1] + ue.y;
        *(float2*)&s_mem[m * 66 + 2 * f] = res;
    }
    __syncthreads();

    // ---- phase 2: member attention (att_w1 lo-half from global, L1-hot) ----
    {
        int m = tid >> 4, j = tid & 15;
        float acc = s_ipart[j];
        #pragma unroll
        for (int d = 0; d < 64; ++d)
            acc += s_mem[m * 66 + d] * att_w1[d * 16 + j];
        float contrib = fmaxf(acc, 0.f) * att_w2[j];
        #pragma unroll
        for (int mk = 8; mk >= 1; mk >>= 1) contrib += __shfl_xor(contrib, mk);
        if (j == 0) s_score[m] = contrib + att_b2[0];
    }
    __syncthreads();
    if (tid < 16) {
        float s = s_score[tid];
        float mx2 = s;
        #pragma unroll
        for (int mk = 8; mk >= 1; mk >>= 1) mx2 = fmaxf(mx2, __shfl_xor(mx2, mk));
        float e2 = __expf(s - mx2);
        float sm2 = e2;
        #pragma unroll
        for (int mk = 8; mk >= 1; mk >>= 1) sm2 += __shfl_xor(sm2, mk);
        s_mw[tid] = e2 / sm2;
    }
    __syncthreads();
    if (tid < 64) {
        float g = s_gemb[tid];
        #pragma unroll
        for (int mm = 0; mm < 16; ++mm)
            g += s_mw[mm] * s_mem[mm * 66 + tid];
        s_gfin[tid] = g;
    }
    __syncthreads();

    // ---- phase 3: NCF predict head ----
    if (tid < 8) {
        const int j = tid;
        float acc = pred_b1[j];
        #pragma unroll 16
        for (int k = 0; k < 64; ++k) {
            float g = s_gfin[k], ie = s_iemb[k];
            acc += (g * ie) * pred_w1[k * 8 + j];
            acc += g  * pred_w1[(64 + k) * 8 + j];
            acc += ie * pred_w1[(128 + k) * 8 + j];
        }
        float contrib = fmaxf(acc, 0.f) * pred_w2[j];
        #pragma unroll
        for (int mk = 4; mk >= 1; mk >>= 1) contrib += __shfl_xor(contrib, mk);
        if (j == 0) {
            float z = contrib + pred_b2[0];
            out[b] = 1.f / (1.f + __expf(-z));
        }
    }
}

extern "C" void kernel_launch(void* const* d_in, const int* in_sizes, int n_in,
                              void* d_out, int out_size, void* d_ws, size_t ws_size,
                              hipStream_t stream) {
    const int*   group_inputs = (const int*)d_in[0];
    const int*   item_inputs  = (const int*)d_in[1];
    const int*   member_ids   = (const int*)d_in[2];
    const int*   follow_ids   = (const int*)d_in[3];
    const float* user_table   = (const float*)d_in[4];
    const float* item_table   = (const float*)d_in[5];
    const float* group_table  = (const float*)d_in[6];
    const float* follow_table = (const float*)d_in[7];
    const float* fatt_w1 = (const float*)d_in[8];
    const float* fatt_b1 = (const float*)d_in[9];
    const float* fatt_w2 = (const float*)d_in[10];
    const float* fatt_b2 = (const float*)d_in[11];
    const float* att_w1  = (const float*)d_in[12];
    const float* att_b1  = (const float*)d_in[13];
    const float* att_w2  = (const float*)d_in[14];
    const float* att_b2  = (const float*)d_in[15];
    const float* pred_w1 = (const float*)d_in[16];
    const float* pred_b1 = (const float*)d_in[17];
    const float* pred_w2 = (const float*)d_in[18];
    const float* pred_b2 = (const float*)d_in[19];
    float* outp = (float*)d_out;

    const int B = in_sizes[0];   // 1024
    const int lds_bytes = LDS_FLOATS * 4;  // 143552

    hipFuncSetAttribute((const void*)soagree_kernel,
                        hipFuncAttributeMaxDynamicSharedMemorySize, lds_bytes);

    soagree_kernel<<<B, 256, lds_bytes, stream>>>(
        group_inputs, item_inputs, member_ids, follow_ids,
        user_table, item_table, group_table, follow_table,
        fatt_w1, fatt_b1, fatt_w2, fatt_b2,
        att_w1, att_b1, att_w2, att_b2,
        pred_w1, pred_b1, pred_w2, pred_b2,
        outp);
}

// Round 7
// 54.813 us; speedup vs baseline: 1.4837x; 1.4837x over previous
//
#include <hip/hip_runtime.h>
#include <math.h>

// SoAGREE fused forward. One block (256 thr = 4 waves) per batch element.
// B=1024, M=16, F=32, D=64, fp32.
// Phase 1: wave w processes member PAIRS (w*4+2pr, w*4+2pr+1), pr=0,1.
//   lane = (f = lane&31, mh = lane>>5): member m = pairbase + mh, row f.
//   Each lane gathers its FULL 256B follow row into 16 float4 regs.
//   Score MLP: d is wave-uniform -> fatt_w1 rows come in as s_load (SGPR),
//   FMAs use the scalar operand -> zero LDS traffic for weights.
//   Weighted sum: scaled rows -> small per-wave half-d LDS tile -> column reads.
// NOTE: this exact structure measured best end-to-end (timed 52.9 us,
// FETCH 69 MB @ ~0.92 TB/s L2-miss BW). Later variants (free-running
// butterfly, DMA double-buffer) did not beat it: duration tracks
// FETCH/0.9 TB/s across all structures -> random-gather service-rate wall.

#define TROW 36                 // padded row stride (floats) in the transpose tile
#define TMH  (32 * TROW + 16)   // mh-section stride; +16 floats = 64B bank offset

__global__ __launch_bounds__(256, 3) void soagree_kernel(
    const int* __restrict__ group_inputs,   // [B]
    const int* __restrict__ item_inputs,    // [B]
    const int* __restrict__ member_ids,     // [B,16]
    const int* __restrict__ follow_ids,     // [B,16,32]
    const float* __restrict__ user_table,   // [NU,64]
    const float* __restrict__ item_table,   // [NI,64]
    const float* __restrict__ group_table,  // [NG,64]
    const float* __restrict__ follow_table, // [NU,64]
    const float* __restrict__ fatt_w1, const float* __restrict__ fatt_b1,
    const float* __restrict__ fatt_w2, const float* __restrict__ fatt_b2,
    const float* __restrict__ att_w1,  const float* __restrict__ att_b1,
    const float* __restrict__ att_w2,  const float* __restrict__ att_b2,
    const float* __restrict__ pred_w1, const float* __restrict__ pred_b1,
    const float* __restrict__ pred_w2, const float* __restrict__ pred_b2,
    float* __restrict__ out)               // [B]
{
    const int b    = blockIdx.x;
    const int tid  = threadIdx.x;
    const int w    = tid >> 6;    // wave id 0..3
    const int lane = tid & 63;
    const int f    = lane & 31;   // follow row / d-index within half
    const int mh   = lane >> 5;   // which member of the pair

    __shared__ float s_tile[4][2 * TMH];  // per-wave transpose tile (half-d)
    __shared__ float s_uemb[16][65];      // member user embeddings (padded)
    __shared__ float s_mem[16][65];       // aggregated member vectors (padded)
    __shared__ float s_upart[16][16];     // u @ fatt_w1[64:] + fatt_b1
    __shared__ float s_ipart[16];         // i @ att_w1[64:] + att_b1
    __shared__ float s_iemb[64];
    __shared__ float s_gemb[64];
    __shared__ float s_gfin[64];
    __shared__ float s_scores[16];
    __shared__ float s_mw[16];

    // ---- phase 0: stage embeddings ----
    if (tid < 64) {
        s_iemb[tid] = item_table[(size_t)item_inputs[b] * 64 + tid];
    } else if (tid < 128) {
        s_gemb[tid - 64] = group_table[(size_t)group_inputs[b] * 64 + (tid - 64)];
    }
    for (int m = w; m < 16; m += 4) {
        int uid = member_ids[b * 16 + m];
        s_uemb[m][lane] = user_table[(size_t)uid * 64 + lane];
    }
    __syncthreads();

    // ---- phase 0.5: u_part[m][j], i_part[j] (w1 hi-halves from global, L1-hot) ----
    {
        int m = tid >> 4, j = tid & 15;
        float acc = fatt_b1[j];
        #pragma unroll
        for (int d = 0; d < 64; ++d)
            acc += s_uemb[m][d] * fatt_w1[(64 + d) * 16 + j];
        s_upart[m][j] = acc;
    }
    if (tid < 16) {
        float a2 = att_b1[tid];
        #pragma unroll
        for (int d = 0; d < 64; ++d)
            a2 += s_iemb[d] * att_w1[(64 + d) * 16 + tid];
        s_ipart[tid] = a2;
    }
    __syncthreads();

    float* const tw_base = &s_tile[w][0];

    // ---- phase 1: follow attention, 2 member-pairs per wave, wave-local ----
    #pragma unroll
    for (int pr = 0; pr < 2; ++pr) {
        const int pb = w * 4 + pr * 2;   // pair's first member
        const int m  = pb + mh;          // this lane's member

        // gather: one coalesced id load, then full 256B row -> 16 float4 regs
        const int fid = follow_ids[b * 512 + pb * 32 + lane];
        const float4* src = (const float4*)(follow_table + (size_t)fid * 64);
        float4 r[16];
        #pragma unroll
        for (int q = 0; q < 16; ++q) r[q] = src[q];

        // hacc init from s_upart (2-addr broadcast b128 reads)
        float hacc[16];
        #pragma unroll
        for (int jj = 0; jj < 4; ++jj) {
            float4 up = *(const float4*)&s_upart[m][jj * 4];
            hacc[jj * 4 + 0] = up.x; hacc[jj * 4 + 1] = up.y;
            hacc[jj * 4 + 2] = up.z; hacc[jj * 4 + 3] = up.w;
        }

        // score MLP: d wave-uniform -> fatt_w1[d*16+j] is a scalar (s_load) operand
        const float* rf = (const float*)r;
        #pragma unroll
        for (int d = 0; d < 64; ++d) {
            const float v = rf[d];
            #pragma unroll
            for (int j = 0; j < 16; ++j)
                hacc[j] += v * fatt_w1[d * 16 + j];
        }
        float sc = fatt_b2[0];
        #pragma unroll
        for (int j = 0; j < 16; ++j)
            sc += fmaxf(hacc[j], 0.f) * fatt_w2[j];

        // softmax over the 32 f-lanes of this half (masks <32 stay in-half)
        float mx = sc;
        #pragma unroll
        for (int mk = 16; mk >= 1; mk >>= 1) mx = fmaxf(mx, __shfl_xor(mx, mk));
        const float e = __expf(sc - mx);
        float se = e;
        #pragma unroll
        for (int mk = 16; mk >= 1; mk >>= 1) se += __shfl_xor(se, mk);
        const float fwv = e / se;

        float* const tw = tw_base + mh * TMH + f * TROW;

        // --- d-lo: scaled rows -> tile -> column reduce ---
        #pragma unroll
        for (int q = 0; q < 8; ++q) {
            float4 sr;
            sr.x = r[q].x * fwv; sr.y = r[q].y * fwv;
            sr.z = r[q].z * fwv; sr.w = r[q].w * fwv;
            *(float4*)&tw[q * 4] = sr;
        }
        asm volatile("s_waitcnt lgkmcnt(0)" ::: "memory");
        __builtin_amdgcn_sched_barrier(0);
        {
            float acc = s_uemb[m][f];
            #pragma unroll
            for (int ff = 0; ff < 32; ++ff)
                acc += tw_base[mh * TMH + ff * TROW + f];
            s_mem[m][f] = acc;
        }
        asm volatile("s_waitcnt lgkmcnt(0)" ::: "memory");
        __builtin_amdgcn_sched_barrier(0);

        // --- d-hi: reuse the same tile slots ---
        #pragma unroll
        for (int q = 8; q < 16; ++q) {
            float4 sr;
            sr.x = r[q].x * fwv; sr.y = r[q].y * fwv;
            sr.z = r[q].z * fwv; sr.w = r[q].w * fwv;
            *(float4*)&tw[(q - 8) * 4] = sr;
        }
        asm volatile("s_waitcnt lgkmcnt(0)" ::: "memory");
        __builtin_amdgcn_sched_barrier(0);
        {
            float acc = s_uemb[m][f + 32];
            #pragma unroll
            for (int ff = 0; ff < 32; ++ff)
                acc += tw_base[mh * TMH + ff * TROW + f];
            s_mem[m][f + 32] = acc;
        }
        asm volatile("s_waitcnt lgkmcnt(0)" ::: "memory");
        __builtin_amdgcn_sched_barrier(0);
    }
    __syncthreads();

    // ---- phase 2: member attention (att_w1 lo-half from global, L1-hot) ----
    {
        int m = tid >> 4, j = tid & 15;
        float acc = s_ipart[j];
        #pragma unroll
        for (int d = 0; d < 64; ++d)
            acc += s_mem[m][d] * att_w1[d * 16 + j];
        float contrib = fmaxf(acc, 0.f) * att_w2[j];
        #pragma unroll
        for (int mk = 8; mk >= 1; mk >>= 1) contrib += __shfl_xor(contrib, mk);
        if (j == 0) s_scores[m] = contrib + att_b2[0];
    }
    __syncthreads();
    if (tid < 16) {
        float s = s_scores[tid];
        float mx2 = s;
        #pragma unroll
        for (int mk = 8; mk >= 1; mk >>= 1) mx2 = fmaxf(mx2, __shfl_xor(mx2, mk));
        float e2 = __expf(s - mx2);
        float sm2 = e2;
        #pragma unroll
        for (int mk = 8; mk >= 1; mk >>= 1) sm2 += __shfl_xor(sm2, mk);
        s_mw[tid] = e2 / sm2;
    }
    __syncthreads();
    if (tid < 64) {
        float g = s_gemb[tid];
        #pragma unroll
        for (int mm = 0; mm < 16; ++mm)
            g += s_mw[mm] * s_mem[mm][tid];
        s_gfin[tid] = g;
    }
    __syncthreads();

    // ---- phase 3: NCF predict head ----
    if (tid < 8) {
        const int j = tid;
        float acc = pred_b1[j];
        #pragma unroll 16
        for (int k = 0; k < 64; ++k) {
            float g = s_gfin[k], ie = s_iemb[k];
            acc += (g * ie) * pred_w1[k * 8 + j];
            acc += g  * pred_w1[(64 + k) * 8 + j];
            acc += ie * pred_w1[(128 + k) * 8 + j];
        }
        float contrib = fmaxf(acc, 0.f) * pred_w2[j];
        #pragma unroll
        for (int mk = 4; mk >= 1; mk >>= 1) contrib += __shfl_xor(contrib, mk);
        if (j == 0) {
            float z = contrib + pred_b2[0];
            out[b] = 1.f / (1.f + __expf(-z));
        }
    }
}

extern "C" void kernel_launch(void* const* d_in, const int* in_sizes, int n_in,
                              void* d_out, int out_size, void* d_ws, size_t ws_size,
                              hipStream_t stream) {
    const int*   group_inputs = (const int*)d_in[0];
    const int*   item_inputs  = (const int*)d_in[1];
    const int*   member_ids   = (const int*)d_in[2];
    const int*   follow_ids   = (const int*)d_in[3];
    const float* user_table   = (const float*)d_in[4];
    const float* item_table   = (const float*)d_in[5];
    const float* group_table  = (const float*)d_in[6];
    const float* follow_table = (const float*)d_in[7];
    const float* fatt_w1 = (const float*)d_in[8];
    const float* fatt_b1 = (const float*)d_in[9];
    const float* fatt_w2 = (const float*)d_in[10];
    const float* fatt_b2 = (const float*)d_in[11];
    const float* att_w1  = (const float*)d_in[12];
    const float* att_b1  = (const float*)d_in[13];
    const float* att_w2  = (const float*)d_in[14];
    const float* att_b2  = (const float*)d_in[15];
    const float* pred_w1 = (const float*)d_in[16];
    const float* pred_b1 = (const float*)d_in[17];
    const float* pred_w2 = (const float*)d_in[18];
    const float* pred_b2 = (const float*)d_in[19];
    float* outp = (float*)d_out;

    const int B = in_sizes[0];   // 1024

    soagree_kernel<<<B, 256, 0, stream>>>(
        group_inputs, item_inputs, member_ids, follow_ids,
        user_table, item_table, group_table, follow_table,
        fatt_w1, fatt_b1, fatt_w2, fatt_b2,
        att_w1, att_b1, att_w2, att_b2,
        pred_w1, pred_b1, pred_w2, pred_b2,
        outp);
}